// Round 4
// baseline (16149.927 us; speedup 1.0000x reference)
//
#include <hip/hip_runtime.h>
#include <hip/hip_bf16.h>
#include <math.h>

#define N_NODES 50000
#define N_EDGES 800000
#define NHID    256
#define LN_EPS  1e-5f

// -------------------- h = x @ W^T + b  (fp32) --------------------
// Block: 256 threads, computes 32 rows x 256 cols. K tiled by 32.
// LDS: xs[k][r] (transposed x tile, 32KB) + ws[k][c] (transposed W tile, 32KB).
__global__ __launch_bounds__(256) void gemm_xwt(const float* __restrict__ x,
                                                const float* __restrict__ W,
                                                const float* __restrict__ bias,
                                                float* __restrict__ h, int n_rows)
{
    __shared__ float xs[NHID][32];   // [k][r]
    __shared__ float ws[32][NHID];   // [k][c]
    const int tid  = threadIdx.x;
    const int row0 = blockIdx.x * 32;

    // Stage x tile transposed: thread -> row r=tid&31, k chunk (tid>>5)*32
    {
        const int r  = tid & 31;
        const int k0 = (tid >> 5) << 5;
        const int grow = row0 + r;
        if (grow < n_rows) {
            const float4* xp4 = (const float4*)(x + (size_t)grow * NHID + k0);
            #pragma unroll
            for (int j = 0; j < 8; ++j) {
                float4 u = xp4[j];
                const int kk = k0 + j * 4;
                xs[kk + 0][r] = u.x;
                xs[kk + 1][r] = u.y;
                xs[kk + 2][r] = u.z;
                xs[kk + 3][r] = u.w;
            }
        } else {
            #pragma unroll
            for (int j = 0; j < 32; ++j) xs[k0 + j][r] = 0.f;
        }
    }

    const int tx = tid & 63;   // cols tx*4 .. tx*4+3
    const int ty = tid >> 6;   // rows ty*8 .. ty*8+7
    float acc[8][4];
    #pragma unroll
    for (int r = 0; r < 8; ++r)
        #pragma unroll
        for (int c = 0; c < 4; ++c) acc[r][c] = 0.f;

    for (int kt = 0; kt < NHID; kt += 32) {
        __syncthreads();   // protect ws reads of previous tile (also covers xs staging on iter 0)
        // Stage W tile transposed: thread -> col c=tid, k = kt..kt+31
        {
            const float4* wp4 = (const float4*)(W + (size_t)tid * NHID + kt);
            #pragma unroll
            for (int j = 0; j < 8; ++j) {
                float4 u = wp4[j];
                const int kk = j * 4;
                ws[kk + 0][tid] = u.x;
                ws[kk + 1][tid] = u.y;
                ws[kk + 2][tid] = u.z;
                ws[kk + 3][tid] = u.w;
            }
        }
        __syncthreads();
        #pragma unroll 4
        for (int k = 0; k < 32; ++k) {
            const float4 wv = *(const float4*)&ws[k][tx * 4];
            const float4 xa = *(const float4*)&xs[kt + k][ty * 8];
            const float4 xb = *(const float4*)&xs[kt + k][ty * 8 + 4];
            const float xr[8] = {xa.x, xa.y, xa.z, xa.w, xb.x, xb.y, xb.z, xb.w};
            #pragma unroll
            for (int r = 0; r < 8; ++r) {
                acc[r][0] += xr[r] * wv.x;
                acc[r][1] += xr[r] * wv.y;
                acc[r][2] += xr[r] * wv.z;
                acc[r][3] += xr[r] * wv.w;
            }
        }
    }

    // Epilogue: + bias, store fp32
    const float4 bv = *(const float4*)(bias + tx * 4);
    #pragma unroll
    for (int r = 0; r < 8; ++r) {
        const int grow = row0 + ty * 8 + r;
        if (grow < n_rows) {
            float4 o;
            o.x = acc[r][0] + bv.x; o.y = acc[r][1] + bv.y;
            o.z = acc[r][2] + bv.z; o.w = acc[r][3] + bv.w;
            *(float4*)&h[(size_t)grow * NHID + tx * 4] = o;
        }
    }
}

// -------------------- out[row] += val * in[col]  (edge-parallel scatter) --------------------
// One wave per edge; lane handles 4 contiguous features.
__global__ __launch_bounds__(256) void spmm_scatter(const int* __restrict__ rows_all,
                                                    const int* __restrict__ cols_all,
                                                    const float* __restrict__ vals_all,
                                                    const int* __restrict__ idx_arr, int idx_pos,
                                                    const float* __restrict__ in,
                                                    float* __restrict__ out)
{
    const int a = idx_arr[idx_pos];
    const size_t base = (size_t)a * N_EDGES;
    const int e = blockIdx.x * 4 + (threadIdx.x >> 6);
    const int lane = threadIdx.x & 63;
    const int r = rows_all[base + e];
    const int c = cols_all[base + e];
    const float v = vals_all[base + e];
    const float4 src = *(const float4*)(in + (size_t)c * NHID + lane * 4);
    float* dst = out + (size_t)r * NHID + lane * 4;
    atomicAdd(dst + 0, v * src.x);
    atomicAdd(dst + 1, v * src.y);
    atomicAdd(dst + 2, v * src.z);
    atomicAdd(dst + 3, v * src.w);
}

// -------------------- LayerNorm + exact GELU, fp32 out --------------------
// One wave per row.
__global__ __launch_bounds__(256) void ln_gelu_k(const float* __restrict__ s,
                                                 const float* __restrict__ gamma,
                                                 const float* __restrict__ beta,
                                                 float* __restrict__ out, int n_rows)
{
    const int wave = (blockIdx.x * blockDim.x + threadIdx.x) >> 6;
    const int lane = threadIdx.x & 63;
    if (wave >= n_rows) return;
    const float4 v = *(const float4*)(s + (size_t)wave * NHID + lane * 4);
    float sum = v.x + v.y + v.z + v.w;
    float sq  = v.x * v.x + v.y * v.y + v.z * v.z + v.w * v.w;
    #pragma unroll
    for (int off = 1; off < 64; off <<= 1) {
        sum += __shfl_xor(sum, off, 64);
        sq  += __shfl_xor(sq,  off, 64);
    }
    const float mu   = sum * (1.f / NHID);
    const float var  = sq * (1.f / NHID) - mu * mu;
    const float rstd = rsqrtf(var + LN_EPS);

    const float4 g4 = *(const float4*)(gamma + lane * 4);
    const float4 b4 = *(const float4*)(beta + lane * 4);
    const float g[4]  = {g4.x, g4.y, g4.z, g4.w};
    const float bb[4] = {b4.x, b4.y, b4.z, b4.w};
    const float in4[4] = {v.x, v.y, v.z, v.w};
    float4 o;
    float* op = (float*)&o;
    #pragma unroll
    for (int j = 0; j < 4; ++j) {
        const float y = (in4[j] - mu) * rstd * g[j] + bb[j];
        op[j] = 0.5f * y * (1.f + erff(y * 0.70710678118654752f));
    }
    *(float4*)(out + (size_t)wave * NHID + lane * 4) = o;
}

extern "C" void kernel_launch(void* const* d_in, const int* in_sizes, int n_in,
                              void* d_out, int out_size, void* d_ws, size_t ws_size,
                              hipStream_t stream)
{
    (void)in_sizes; (void)n_in; (void)out_size; (void)ws_size;
    const float* x        = (const float*)d_in[0];
    const int* adj_rows   = (const int*)d_in[1];
    const int* adj_cols   = (const int*)d_in[2];
    const float* vals     = (const float*)d_in[3];
    const int* idx_seq    = (const int*)d_in[4];
    const int* idx_res    = (const int*)d_in[5];
    const float* W        = (const float*)d_in[6];
    const float* bias     = (const float*)d_in[7];
    const float* gam      = (const float*)d_in[8];
    const float* bet      = (const float*)d_in[9];

    const size_t S = (size_t)N_NODES * NHID;
    float* s0 = (float*)d_ws;
    float* s1 = s0 + S;
    float* s2 = s1 + S;
    float* s3 = s2 + S;

    // ws is poisoned 0xAA before every timed call: zero the three accumulators.
    hipMemsetAsync(s1, 0, 3 * S * sizeof(float), stream);

    gemm_xwt<<<dim3((N_NODES + 31) / 32), dim3(256), 0, stream>>>(x, W, bias, s0, N_NODES);

    // states[1] = A[seq0] @ s0
    spmm_scatter<<<dim3(N_EDGES / 4), dim3(256), 0, stream>>>(adj_rows, adj_cols, vals, idx_seq, 0, s0, s1);
    // states[2] = A[seq1] @ s1 + A[res0] @ s0
    spmm_scatter<<<dim3(N_EDGES / 4), dim3(256), 0, stream>>>(adj_rows, adj_cols, vals, idx_seq, 1, s1, s2);
    spmm_scatter<<<dim3(N_EDGES / 4), dim3(256), 0, stream>>>(adj_rows, adj_cols, vals, idx_res, 0, s0, s2);
    // states[3] = A[seq2] @ s2 + A[res1] @ s0 + A[res2] @ s1
    spmm_scatter<<<dim3(N_EDGES / 4), dim3(256), 0, stream>>>(adj_rows, adj_cols, vals, idx_seq, 2, s2, s3);
    spmm_scatter<<<dim3(N_EDGES / 4), dim3(256), 0, stream>>>(adj_rows, adj_cols, vals, idx_res, 1, s0, s3);
    spmm_scatter<<<dim3(N_EDGES / 4), dim3(256), 0, stream>>>(adj_rows, adj_cols, vals, idx_res, 2, s1, s3);

    ln_gelu_k<<<dim3((N_NODES + 3) / 4), dim3(256), 0, stream>>>(s3, gam, bet, (float*)d_out, N_NODES);
}

// Round 5
// 1426.523 us; speedup vs baseline: 11.3212x; 11.3212x over previous
//
#include <hip/hip_runtime.h>
#include <hip/hip_bf16.h>
#include <math.h>

#define N_NODES 50000
#define N_EDGES 800000
#define N_ADJS  6
#define NHID    256
#define LN_EPS  1e-5f

// -------------------- h = x @ W^T + b  (fp32) --------------------
__global__ __launch_bounds__(256) void gemm_xwt(const float* __restrict__ x,
                                                const float* __restrict__ W,
                                                const float* __restrict__ bias,
                                                float* __restrict__ h, int n_rows)
{
    __shared__ float xs[NHID][32];   // [k][r]
    __shared__ float ws[32][NHID];   // [k][c]
    const int tid  = threadIdx.x;
    const int row0 = blockIdx.x * 32;

    {
        const int r  = tid & 31;
        const int k0 = (tid >> 5) << 5;
        const int grow = row0 + r;
        if (grow < n_rows) {
            const float4* xp4 = (const float4*)(x + (size_t)grow * NHID + k0);
            #pragma unroll
            for (int j = 0; j < 8; ++j) {
                float4 u = xp4[j];
                const int kk = k0 + j * 4;
                xs[kk + 0][r] = u.x;
                xs[kk + 1][r] = u.y;
                xs[kk + 2][r] = u.z;
                xs[kk + 3][r] = u.w;
            }
        } else {
            #pragma unroll
            for (int j = 0; j < 32; ++j) xs[k0 + j][r] = 0.f;
        }
    }

    const int tx = tid & 63;
    const int ty = tid >> 6;
    float acc[8][4];
    #pragma unroll
    for (int r = 0; r < 8; ++r)
        #pragma unroll
        for (int c = 0; c < 4; ++c) acc[r][c] = 0.f;

    for (int kt = 0; kt < NHID; kt += 32) {
        __syncthreads();
        {
            const float4* wp4 = (const float4*)(W + (size_t)tid * NHID + kt);
            #pragma unroll
            for (int j = 0; j < 8; ++j) {
                float4 u = wp4[j];
                const int kk = j * 4;
                ws[kk + 0][tid] = u.x;
                ws[kk + 1][tid] = u.y;
                ws[kk + 2][tid] = u.z;
                ws[kk + 3][tid] = u.w;
            }
        }
        __syncthreads();
        #pragma unroll 4
        for (int k = 0; k < 32; ++k) {
            const float4 wv = *(const float4*)&ws[k][tx * 4];
            const float4 xa = *(const float4*)&xs[kt + k][ty * 8];
            const float4 xb = *(const float4*)&xs[kt + k][ty * 8 + 4];
            const float xr[8] = {xa.x, xa.y, xa.z, xa.w, xb.x, xb.y, xb.z, xb.w};
            #pragma unroll
            for (int r = 0; r < 8; ++r) {
                acc[r][0] += xr[r] * wv.x;
                acc[r][1] += xr[r] * wv.y;
                acc[r][2] += xr[r] * wv.z;
                acc[r][3] += xr[r] * wv.w;
            }
        }
    }

    const float4 bv = *(const float4*)(bias + tx * 4);
    #pragma unroll
    for (int r = 0; r < 8; ++r) {
        const int grow = row0 + ty * 8 + r;
        if (grow < n_rows) {
            float4 o;
            o.x = acc[r][0] + bv.x; o.y = acc[r][1] + bv.y;
            o.z = acc[r][2] + bv.z; o.w = acc[r][3] + bv.w;
            *(float4*)&h[(size_t)grow * NHID + tx * 4] = o;
        }
    }
}

// -------------------- CSR build: histogram --------------------
__global__ __launch_bounds__(256) void hist_k(const int* __restrict__ rows_all,
                                              int* __restrict__ hist)
{
    const int a = blockIdx.y;
    const int e = blockIdx.x * 256 + threadIdx.x;
    const int r = rows_all[(size_t)a * N_EDGES + e];
    atomicAdd(&hist[(size_t)a * N_NODES + r], 1);
}

// -------------------- CSR build: exclusive scan (one block/adjacency) --------------------
__global__ __launch_bounds__(1024) void scan_rows(const int* __restrict__ hist,
                                                  int* __restrict__ row_start,
                                                  int* __restrict__ cursor)
{
    const int a = blockIdx.x;
    const int* h = hist + (size_t)a * N_NODES;
    int* rs  = row_start + (size_t)a * (N_NODES + 1);
    int* cur = cursor + (size_t)a * N_NODES;
    const int tid = threadIdx.x, lane = tid & 63, wid = tid >> 6;  // 16 waves
    __shared__ int wsum[16];
    __shared__ int carry_s;
    if (tid == 0) carry_s = 0;
    __syncthreads();
    for (int base = 0; base < N_NODES; base += 1024) {
        const int i = base + tid;
        const int v = (i < N_NODES) ? h[i] : 0;
        int x = v;  // inclusive wave scan
        #pragma unroll
        for (int d = 1; d < 64; d <<= 1) {
            int t = __shfl_up(x, d, 64);
            if (lane >= d) x += t;
        }
        if (lane == 63) wsum[wid] = x;
        __syncthreads();
        if (wid == 0 && lane < 16) {
            const int wv = wsum[lane];
            int y = wv;
            #pragma unroll
            for (int d = 1; d < 16; d <<= 1) {
                int t = __shfl_up(y, d, 64);
                if (lane >= d) y += t;
            }
            wsum[lane] = y - wv;  // exclusive wave offset
        }
        __syncthreads();
        const int woff  = wsum[wid];
        const int carry = carry_s;
        const int excl  = carry + woff + x - v;
        if (i < N_NODES) { rs[i] = excl; cur[i] = excl; }
        __syncthreads();
        if (tid == 1023) carry_s = carry + woff + x;
        __syncthreads();
    }
    if (tid == 0) rs[N_NODES] = carry_s;
}

// -------------------- CSR build: fill (col,val) sorted by row --------------------
__global__ __launch_bounds__(256) void fill_csr(const int* __restrict__ rows_all,
                                                const int* __restrict__ cols_all,
                                                const float* __restrict__ vals_all,
                                                int* __restrict__ cursor,
                                                int2* __restrict__ sorted_cv)
{
    const int a = blockIdx.y;
    const size_t idx = (size_t)a * N_EDGES + blockIdx.x * 256 + threadIdx.x;
    const int r = rows_all[idx];
    const int pos = atomicAdd(&cursor[(size_t)a * N_NODES + r], 1);
    int2 cv;
    cv.x = cols_all[idx];
    cv.y = __float_as_int(vals_all[idx]);
    sorted_cv[(size_t)a * N_EDGES + pos] = cv;
}

// -------------------- pull-mode SpMM: one wave per dst row, up to 3 (adj, src) parts --------------------
// Optional fused LayerNorm + exact GELU when gamma != nullptr.
static __device__ __forceinline__ void pull_part(const int* __restrict__ row_start,
                                                 const int2* __restrict__ sorted_cv,
                                                 int a, const float* __restrict__ src,
                                                 int row, int lane, float4& acc)
{
    const int2* cv = sorted_cv + (size_t)a * N_EDGES;
    const int* rs  = row_start + (size_t)a * (N_NODES + 1);
    const int s = rs[row], epnd = rs[row + 1];
    int e = s;
    for (; e + 1 < epnd; e += 2) {
        const int2 p0 = cv[e];
        const int2 p1 = cv[e + 1];
        const float4 g0 = *(const float4*)(src + (size_t)p0.x * NHID + lane * 4);
        const float4 g1 = *(const float4*)(src + (size_t)p1.x * NHID + lane * 4);
        const float v0 = __int_as_float(p0.y);
        const float v1 = __int_as_float(p1.y);
        acc.x += v0 * g0.x; acc.y += v0 * g0.y; acc.z += v0 * g0.z; acc.w += v0 * g0.w;
        acc.x += v1 * g1.x; acc.y += v1 * g1.y; acc.z += v1 * g1.z; acc.w += v1 * g1.w;
    }
    if (e < epnd) {
        const int2 p0 = cv[e];
        const float4 g0 = *(const float4*)(src + (size_t)p0.x * NHID + lane * 4);
        const float v0 = __int_as_float(p0.y);
        acc.x += v0 * g0.x; acc.y += v0 * g0.y; acc.z += v0 * g0.z; acc.w += v0 * g0.w;
    }
}

__global__ __launch_bounds__(256) void pull_spmm(
    const int* __restrict__ row_start, const int2* __restrict__ sorted_cv,
    const int* __restrict__ idx_a, int pos_a, const float* __restrict__ src_a,
    const int* __restrict__ idx_b, int pos_b, const float* __restrict__ src_b,
    const int* __restrict__ idx_c, int pos_c, const float* __restrict__ src_c,
    float* __restrict__ out,
    const float* __restrict__ gamma, const float* __restrict__ beta)
{
    const int row  = (blockIdx.x * 256 + threadIdx.x) >> 6;
    const int lane = threadIdx.x & 63;
    if (row >= N_NODES) return;
    float4 acc = {0.f, 0.f, 0.f, 0.f};
    pull_part(row_start, sorted_cv, idx_a[pos_a], src_a, row, lane, acc);
    if (src_b) pull_part(row_start, sorted_cv, idx_b[pos_b], src_b, row, lane, acc);
    if (src_c) pull_part(row_start, sorted_cv, idx_c[pos_c], src_c, row, lane, acc);

    if (gamma) {
        float sum = acc.x + acc.y + acc.z + acc.w;
        float sq  = acc.x * acc.x + acc.y * acc.y + acc.z * acc.z + acc.w * acc.w;
        #pragma unroll
        for (int off = 1; off < 64; off <<= 1) {
            sum += __shfl_xor(sum, off, 64);
            sq  += __shfl_xor(sq,  off, 64);
        }
        const float mu   = sum * (1.f / NHID);
        const float var  = sq * (1.f / NHID) - mu * mu;
        const float rstd = rsqrtf(var + LN_EPS);
        const float4 g4 = *(const float4*)(gamma + lane * 4);
        const float4 b4 = *(const float4*)(beta + lane * 4);
        float in4[4] = {acc.x, acc.y, acc.z, acc.w};
        const float g[4]  = {g4.x, g4.y, g4.z, g4.w};
        const float bb[4] = {b4.x, b4.y, b4.z, b4.w};
        float4 o; float* op = (float*)&o;
        #pragma unroll
        for (int j = 0; j < 4; ++j) {
            const float y = (in4[j] - mu) * rstd * g[j] + bb[j];
            op[j] = 0.5f * y * (1.f + erff(y * 0.70710678118654752f));
        }
        *(float4*)(out + (size_t)row * NHID + lane * 4) = o;
    } else {
        *(float4*)(out + (size_t)row * NHID + lane * 4) = acc;
    }
}

extern "C" void kernel_launch(void* const* d_in, const int* in_sizes, int n_in,
                              void* d_out, int out_size, void* d_ws, size_t ws_size,
                              hipStream_t stream)
{
    (void)in_sizes; (void)n_in; (void)out_size; (void)ws_size;
    const float* x        = (const float*)d_in[0];
    const int* adj_rows   = (const int*)d_in[1];
    const int* adj_cols   = (const int*)d_in[2];
    const float* vals     = (const float*)d_in[3];
    const int* idx_seq    = (const int*)d_in[4];
    const int* idx_res    = (const int*)d_in[5];
    const float* W        = (const float*)d_in[6];
    const float* bias     = (const float*)d_in[7];
    const float* gam      = (const float*)d_in[8];
    const float* bet      = (const float*)d_in[9];

    const size_t S = (size_t)N_NODES * NHID;
    // Workspace layout (8B-aligned chunks first): s0,s1,s2 | sorted_cv | hist | row_start | cursor
    float* s0 = (float*)d_ws;
    float* s1 = s0 + S;
    float* s2 = s1 + S;
    int2*  sorted_cv = (int2*)(s2 + S);                       // 6*800000*8 B = 38.4 MB
    int*   hist      = (int*)(sorted_cv + (size_t)N_ADJS * N_EDGES);  // 6*50000*4
    int*   row_start = hist + (size_t)N_ADJS * N_NODES;                // 6*50001*4
    int*   cursor    = row_start + (size_t)N_ADJS * (N_NODES + 1);     // 6*50000*4
    // total ≈ 153.6 + 38.4 + 3.6 MB = 195.6 MB

    hipMemsetAsync(hist, 0, (size_t)N_ADJS * N_NODES * sizeof(int), stream);

    gemm_xwt<<<dim3((N_NODES + 31) / 32), dim3(256), 0, stream>>>(x, W, bias, s0, N_NODES);

    // Build CSR for all 6 adjacencies (idx selection happens inside pull_spmm on device)
    hist_k<<<dim3(N_EDGES / 256, N_ADJS), dim3(256), 0, stream>>>(adj_rows, hist);
    scan_rows<<<dim3(N_ADJS), dim3(1024), 0, stream>>>(hist, row_start, cursor);
    fill_csr<<<dim3(N_EDGES / 256, N_ADJS), dim3(256), 0, stream>>>(adj_rows, adj_cols, vals, cursor, sorted_cv);

    const dim3 pgrid(N_NODES * 64 / 256);   // one wave per row, 4 rows/block -> 12500 blocks
    // states[1] = A[seq0] @ s0
    pull_spmm<<<pgrid, dim3(256), 0, stream>>>(row_start, sorted_cv,
        idx_seq, 0, s0,  nullptr, 0, nullptr,  nullptr, 0, nullptr,  s1, nullptr, nullptr);
    // states[2] = A[seq1] @ s1 + A[res0] @ s0
    pull_spmm<<<pgrid, dim3(256), 0, stream>>>(row_start, sorted_cv,
        idx_seq, 1, s1,  idx_res, 0, s0,  nullptr, 0, nullptr,  s2, nullptr, nullptr);
    // out = gelu(layernorm(A[seq2] @ s2 + A[res1] @ s0 + A[res2] @ s1))
    pull_spmm<<<pgrid, dim3(256), 0, stream>>>(row_start, sorted_cv,
        idx_seq, 2, s2,  idx_res, 1, s0,  idx_res, 2, s1,  (float*)d_out, gam, bet);
}

// Round 6
// 1147.700 us; speedup vs baseline: 14.0716x; 1.2429x over previous
//
#include <hip/hip_runtime.h>
#include <math.h>

#define N_NODES 50000
#define N_EDGES 800000
#define N_ADJS  6
#define NHID    256
#define NB      196       // row buckets of 256 rows each: ceil(50000/256)
#define LN_EPS  1e-5f

typedef short bf16x8 __attribute__((ext_vector_type(8)));
typedef float f32x4  __attribute__((ext_vector_type(4)));

static __device__ __forceinline__ unsigned short f2bf(float f) {
    unsigned int x = __float_as_uint(f);
    unsigned int lsb = (x >> 16) & 1u;
    x += 0x7fffu + lsb;               // RTN-even
    return (unsigned short)(x >> 16);
}
static __device__ __forceinline__ float bf2f(unsigned short u) {
    return __uint_as_float(((unsigned int)u) << 16);
}

// -------------------- W -> bf16 hi/lo split --------------------
__global__ __launch_bounds__(256) void convert_w(const float* __restrict__ W,
                                                 unsigned short* __restrict__ Whi,
                                                 unsigned short* __restrict__ Wlo)
{
    const int i = blockIdx.x * 256 + threadIdx.x;   // 65536 total
    const float w = W[i];
    const unsigned short h = f2bf(w);
    Whi[i] = h;
    Wlo[i] = f2bf(w - bf2f(h));
}

// -------------------- h = x @ W^T + b via MFMA (bf16 split, fp32 acc) --------------------
// Block 256 = 4 waves; block computes 64 rows x 256 cols; wave w: rows w*16..w*16+15.
__global__ __launch_bounds__(256) void gemm_mfma(const float* __restrict__ x,
                                                 const unsigned short* __restrict__ Whi,
                                                 const unsigned short* __restrict__ Wlo,
                                                 const float* __restrict__ bias,
                                                 float* __restrict__ h)
{
    const int tid = threadIdx.x;
    const int w = tid >> 6, l = tid & 63;
    const int m = l & 15, q = l >> 4;
    const int row0 = blockIdx.x * 64 + w * 16;
    const int arow = row0 + m;
    const int arow_c = (arow < N_NODES) ? arow : 0;

    f32x4 acc[16];
    #pragma unroll
    for (int nt = 0; nt < 16; ++nt) acc[nt] = (f32x4){0.f, 0.f, 0.f, 0.f};

    for (int kt = 0; kt < NHID; kt += 32) {
        const float* xp = x + (size_t)arow_c * NHID + kt + q * 8;
        const float4 xa = *(const float4*)xp;
        const float4 xb = *(const float4*)(xp + 4);
        const float xv[8] = {xa.x, xa.y, xa.z, xa.w, xb.x, xb.y, xb.z, xb.w};
        bf16x8 ah, al;
        #pragma unroll
        for (int j = 0; j < 8; ++j) {
            const unsigned short hh = f2bf(xv[j]);
            ah[j] = (short)hh;
            al[j] = (short)f2bf(xv[j] - bf2f(hh));
        }
        const int ko = kt + q * 8;
        #pragma unroll
        for (int nt = 0; nt < 16; ++nt) {
            const size_t off = (size_t)(nt * 16 + m) * NHID + ko;
            const bf16x8 bh = *(const bf16x8*)(Whi + off);
            const bf16x8 bl = *(const bf16x8*)(Wlo + off);
            acc[nt] = __builtin_amdgcn_mfma_f32_16x16x32_bf16(ah, bh, acc[nt], 0, 0, 0);
            acc[nt] = __builtin_amdgcn_mfma_f32_16x16x32_bf16(ah, bl, acc[nt], 0, 0, 0);
            acc[nt] = __builtin_amdgcn_mfma_f32_16x16x32_bf16(al, bh, acc[nt], 0, 0, 0);
        }
    }

    // C/D: col = lane&15, row = (lane>>4)*4 + reg
    #pragma unroll
    for (int nt = 0; nt < 16; ++nt) {
        const int col = nt * 16 + m;
        const float bv = bias[col];
        #pragma unroll
        for (int r = 0; r < 4; ++r) {
            const int grow = row0 + q * 4 + r;
            if (grow < N_NODES) h[(size_t)grow * NHID + col] = acc[nt][r] + bv;
        }
    }
}

// -------------------- CSR build, pass A: bucket counts --------------------
__global__ __launch_bounds__(256) void bucket_count(const int* __restrict__ rows_all,
                                                    int* __restrict__ gcount)
{
    const int a = blockIdx.y;
    __shared__ int lcnt[NB];
    for (int i = threadIdx.x; i < NB; i += 256) lcnt[i] = 0;
    __syncthreads();
    const int e0 = blockIdx.x * 1024 + threadIdx.x;
    #pragma unroll
    for (int j = 0; j < 4; ++j) {
        const int e = e0 + j * 256;
        if (e < N_EDGES) {
            const int r = rows_all[(size_t)a * N_EDGES + e];
            atomicAdd(&lcnt[r >> 8], 1);
        }
    }
    __syncthreads();
    for (int i = threadIdx.x; i < NB; i += 256)
        if (lcnt[i]) atomicAdd(&gcount[a * NB + i], lcnt[i]);
}

// -------------------- CSR build: scan bucket counts (wave a scans adjacency a) --------------------
__global__ __launch_bounds__(384) void scan_buckets(const int* __restrict__ gcount,
                                                    int* __restrict__ bstart,
                                                    int* __restrict__ gcur,
                                                    int* __restrict__ row_start)
{
    const int lane = threadIdx.x & 63, a = threadIdx.x >> 6;
    if (a >= N_ADJS) return;
    int carry = 0;
    #pragma unroll
    for (int c = 0; c < 4; ++c) {
        const int i = c * 64 + lane;
        const int v = (i < NB) ? gcount[a * NB + i] : 0;
        int xs = v;
        #pragma unroll
        for (int d = 1; d < 64; d <<= 1) { const int t = __shfl_up(xs, d, 64); if (lane >= d) xs += t; }
        const int excl = carry + xs - v;
        if (i < NB) { bstart[a * (NB + 1) + i] = excl; gcur[a * NB + i] = excl; }
        carry += __shfl(xs, 63, 64);
    }
    if (lane == 0) {
        bstart[a * (NB + 1) + NB] = N_EDGES;
        row_start[(size_t)a * (N_NODES + 1) + N_NODES] = N_EDGES;
    }
}

// -------------------- CSR build, pass B: scatter into buckets (packed row|col, val) --------------------
__global__ __launch_bounds__(256) void bucket_scatter(const int* __restrict__ rows_all,
                                                      const int* __restrict__ cols_all,
                                                      const float* __restrict__ vals_all,
                                                      int* __restrict__ gcur,
                                                      int2* __restrict__ bucketed)
{
    const int a = blockIdx.y;
    __shared__ int lcnt[NB], lbase[NB];
    for (int i = threadIdx.x; i < NB; i += 256) lcnt[i] = 0;
    __syncthreads();
    int bq[4], sq[4]; int2 pq[4];
    const int e0 = blockIdx.x * 1024 + threadIdx.x;
    #pragma unroll
    for (int j = 0; j < 4; ++j) {
        const int e = e0 + j * 256;
        bq[j] = -1;
        if (e < N_EDGES) {
            const size_t idx = (size_t)a * N_EDGES + e;
            const int r = rows_all[idx];
            const int b = r >> 8;
            bq[j] = b;
            sq[j] = atomicAdd(&lcnt[b], 1);
            pq[j].x = (r << 16) | cols_all[idx];
            pq[j].y = __float_as_int(vals_all[idx]);
        }
    }
    __syncthreads();
    for (int i = threadIdx.x; i < NB; i += 256)
        lbase[i] = lcnt[i] ? atomicAdd(&gcur[a * NB + i], lcnt[i]) : 0;
    __syncthreads();
    int2* bk = bucketed + (size_t)a * N_EDGES;
    #pragma unroll
    for (int j = 0; j < 4; ++j)
        if (bq[j] >= 0) bk[lbase[bq[j]] + sq[j]] = pq[j];
}

// -------------------- CSR build, pass C: per-bucket row sort + row_start --------------------
__global__ __launch_bounds__(256) void build_csr(const int2* __restrict__ bucketed,
                                                 const int* __restrict__ bstart,
                                                 int* __restrict__ row_start,
                                                 int2* __restrict__ sorted_cv)
{
    const int a = blockIdx.y, b = blockIdx.x;
    const int s    = bstart[a * (NB + 1) + b];
    const int epnd = bstart[a * (NB + 1) + b + 1];
    __shared__ int cnt[256], cur[256];
    cnt[threadIdx.x] = 0;
    __syncthreads();
    const int2* bk = bucketed + (size_t)a * N_EDGES;
    for (int e = s + threadIdx.x; e < epnd; e += 256) {
        const unsigned p = (unsigned)bk[e].x;
        atomicAdd(&cnt[(p >> 16) & 255], 1);
    }
    __syncthreads();
    const int lane = threadIdx.x & 63, wid = threadIdx.x >> 6;
    if (wid == 0) {
        const int i0 = lane * 4;
        const int c0 = cnt[i0], c1 = cnt[i0 + 1], c2 = cnt[i0 + 2], c3 = cnt[i0 + 3];
        const int sum = c0 + c1 + c2 + c3;
        int xs = sum;
        #pragma unroll
        for (int d = 1; d < 64; d <<= 1) { const int t = __shfl_up(xs, d, 64); if (lane >= d) xs += t; }
        const int base = xs - sum;
        const int o0 = base, o1 = base + c0, o2 = o1 + c1, o3 = o2 + c2;
        cur[i0] = s + o0; cur[i0 + 1] = s + o1; cur[i0 + 2] = s + o2; cur[i0 + 3] = s + o3;
        int* rs = row_start + (size_t)a * (N_NODES + 1);
        const int gr = (b << 8) + i0;
        if (gr + 0 < N_NODES) rs[gr + 0] = s + o0;
        if (gr + 1 < N_NODES) rs[gr + 1] = s + o1;
        if (gr + 2 < N_NODES) rs[gr + 2] = s + o2;
        if (gr + 3 < N_NODES) rs[gr + 3] = s + o3;
    }
    __syncthreads();
    int2* sc = sorted_cv + (size_t)a * N_EDGES;
    for (int e = s + threadIdx.x; e < epnd; e += 256) {
        const int2 p = bk[e];
        const unsigned r = ((unsigned)p.x) >> 16;
        const int pos = atomicAdd(&cur[r & 255], 1);
        int2 cv; cv.x = p.x & 0xFFFF; cv.y = p.y;
        sc[pos] = cv;
    }
}

// -------------------- pull-mode SpMM (unchanged from R5) --------------------
static __device__ __forceinline__ void pull_part(const int* __restrict__ row_start,
                                                 const int2* __restrict__ sorted_cv,
                                                 int a, const float* __restrict__ src,
                                                 int row, int lane, float4& acc)
{
    const int2* cv = sorted_cv + (size_t)a * N_EDGES;
    const int* rs  = row_start + (size_t)a * (N_NODES + 1);
    const int s = rs[row], epnd = rs[row + 1];
    int e = s;
    for (; e + 1 < epnd; e += 2) {
        const int2 p0 = cv[e];
        const int2 p1 = cv[e + 1];
        const float4 g0 = *(const float4*)(src + (size_t)p0.x * NHID + lane * 4);
        const float4 g1 = *(const float4*)(src + (size_t)p1.x * NHID + lane * 4);
        const float v0 = __int_as_float(p0.y);
        const float v1 = __int_as_float(p1.y);
        acc.x += v0 * g0.x; acc.y += v0 * g0.y; acc.z += v0 * g0.z; acc.w += v0 * g0.w;
        acc.x += v1 * g1.x; acc.y += v1 * g1.y; acc.z += v1 * g1.z; acc.w += v1 * g1.w;
    }
    if (e < epnd) {
        const int2 p0 = cv[e];
        const float4 g0 = *(const float4*)(src + (size_t)p0.x * NHID + lane * 4);
        const float v0 = __int_as_float(p0.y);
        acc.x += v0 * g0.x; acc.y += v0 * g0.y; acc.z += v0 * g0.z; acc.w += v0 * g0.w;
    }
}

__global__ __launch_bounds__(256) void pull_spmm(
    const int* __restrict__ row_start, const int2* __restrict__ sorted_cv,
    const int* __restrict__ idx_a, int pos_a, const float* __restrict__ src_a,
    const int* __restrict__ idx_b, int pos_b, const float* __restrict__ src_b,
    const int* __restrict__ idx_c, int pos_c, const float* __restrict__ src_c,
    float* __restrict__ out,
    const float* __restrict__ gamma, const float* __restrict__ beta)
{
    const int row  = (blockIdx.x * 256 + threadIdx.x) >> 6;
    const int lane = threadIdx.x & 63;
    if (row >= N_NODES) return;
    float4 acc = {0.f, 0.f, 0.f, 0.f};
    pull_part(row_start, sorted_cv, idx_a[pos_a], src_a, row, lane, acc);
    if (src_b) pull_part(row_start, sorted_cv, idx_b[pos_b], src_b, row, lane, acc);
    if (src_c) pull_part(row_start, sorted_cv, idx_c[pos_c], src_c, row, lane, acc);

    if (gamma) {
        float sum = acc.x + acc.y + acc.z + acc.w;
        float sq  = acc.x * acc.x + acc.y * acc.y + acc.z * acc.z + acc.w * acc.w;
        #pragma unroll
        for (int off = 1; off < 64; off <<= 1) {
            sum += __shfl_xor(sum, off, 64);
            sq  += __shfl_xor(sq,  off, 64);
        }
        const float mu   = sum * (1.f / NHID);
        const float var  = sq * (1.f / NHID) - mu * mu;
        const float rstd = rsqrtf(var + LN_EPS);
        const float4 g4 = *(const float4*)(gamma + lane * 4);
        const float4 b4 = *(const float4*)(beta + lane * 4);
        const float in4[4] = {acc.x, acc.y, acc.z, acc.w};
        const float g[4]  = {g4.x, g4.y, g4.z, g4.w};
        const float bb[4] = {b4.x, b4.y, b4.z, b4.w};
        float4 o; float* op = (float*)&o;
        #pragma unroll
        for (int j = 0; j < 4; ++j) {
            const float y = (in4[j] - mu) * rstd * g[j] + bb[j];
            op[j] = 0.5f * y * (1.f + erff(y * 0.70710678118654752f));
        }
        *(float4*)(out + (size_t)row * NHID + lane * 4) = o;
    } else {
        *(float4*)(out + (size_t)row * NHID + lane * 4) = acc;
    }
}

extern "C" void kernel_launch(void* const* d_in, const int* in_sizes, int n_in,
                              void* d_out, int out_size, void* d_ws, size_t ws_size,
                              hipStream_t stream)
{
    (void)in_sizes; (void)n_in; (void)out_size; (void)ws_size;
    const float* x        = (const float*)d_in[0];
    const int* adj_rows   = (const int*)d_in[1];
    const int* adj_cols   = (const int*)d_in[2];
    const float* vals     = (const float*)d_in[3];
    const int* idx_seq    = (const int*)d_in[4];
    const int* idx_res    = (const int*)d_in[5];
    const float* W        = (const float*)d_in[6];
    const float* bias     = (const float*)d_in[7];
    const float* gam      = (const float*)d_in[8];
    const float* bet      = (const float*)d_in[9];

    const size_t S = (size_t)N_NODES * NHID;
    float* s0 = (float*)d_ws;
    float* s1 = s0 + S;
    float* s2 = s1 + S;
    int2*  sorted_cv      = (int2*)(s2 + S);                                  // 38.4 MB
    int*   row_start      = (int*)(sorted_cv + (size_t)N_ADJS * N_EDGES);     // 1.2 MB
    unsigned short* Whi   = (unsigned short*)(row_start + (size_t)N_ADJS * (N_NODES + 1)); // 128 KB
    unsigned short* Wlo   = Whi + NHID * NHID;                                // 128 KB
    int*   gcount         = (int*)(Wlo + NHID * NHID);
    int*   bstart         = gcount + N_ADJS * NB;
    int*   gcur           = bstart + N_ADJS * (NB + 1);
    int2*  bucketed       = (int2*)s1;   // aliases s1: dead until pull1 writes it (after build_csr)

    hipMemsetAsync(gcount, 0, (size_t)N_ADJS * NB * sizeof(int), stream);

    convert_w<<<dim3(NHID * NHID / 256), dim3(256), 0, stream>>>(W, Whi, Wlo);
    gemm_mfma<<<dim3((N_NODES + 63) / 64), dim3(256), 0, stream>>>(x, Whi, Wlo, bias, s0);

    const int eblocks = (N_EDGES + 1023) / 1024;
    bucket_count<<<dim3(eblocks, N_ADJS), dim3(256), 0, stream>>>(adj_rows, gcount);
    scan_buckets<<<dim3(1), dim3(384), 0, stream>>>(gcount, bstart, gcur, row_start);
    bucket_scatter<<<dim3(eblocks, N_ADJS), dim3(256), 0, stream>>>(adj_rows, adj_cols, vals, gcur, bucketed);
    build_csr<<<dim3(NB, N_ADJS), dim3(256), 0, stream>>>(bucketed, bstart, row_start, sorted_cv);

    const dim3 pgrid(N_NODES * 64 / 256);
    pull_spmm<<<pgrid, dim3(256), 0, stream>>>(row_start, sorted_cv,
        idx_seq, 0, s0,  nullptr, 0, nullptr,  nullptr, 0, nullptr,  s1, nullptr, nullptr);
    pull_spmm<<<pgrid, dim3(256), 0, stream>>>(row_start, sorted_cv,
        idx_seq, 1, s1,  idx_res, 0, s0,  nullptr, 0, nullptr,  s2, nullptr, nullptr);
    pull_spmm<<<pgrid, dim3(256), 0, stream>>>(row_start, sorted_cv,
        idx_seq, 2, s2,  idx_res, 1, s0,  idx_res, 2, s1,  (float*)d_out, gam, bet);
}